// Round 17
// baseline (63.840 us; speedup 1.0000x reference)
//
#include <hip/hip_runtime.h>
#include <math.h>

#define NCLS 91
#define FDIM 256
#define NB   512                   // mainpass blocks (= partials), 2 per CU
#define BINSZ  (NCLS * FDIM)       // 23296
#define BINSZP (92 * FDIM)         // 23552, padded stride (4-class reduce tiles)
#define NRED 8                     // stage-1 reduction: 8 groups of 64 partials

typedef float f32x4 __attribute__((ext_vector_type(4)));
typedef short short8 __attribute__((ext_vector_type(8)));

__device__ __forceinline__ float wave_sum64(float ss) {
    #pragma unroll
    for (int m = 1; m < 64; m <<= 1) ss += __shfl_xor(ss, m, 64);
    return ss;
}
__device__ __forceinline__ int wave_sum64_i(int v) {
    #pragma unroll
    for (int m = 1; m < 64; m <<= 1) v += __shfl_xor(v, m, 64);
    return v;
}

template <int CTRL>
__device__ __forceinline__ float dpp_addstep(float v) {
    return v + __int_as_float(__builtin_amdgcn_mov_dpp(
        __float_as_int(v), CTRL, 0xf, 0xf, true));
}
__device__ __forceinline__ float group16_sum(float v) {
    v = dpp_addstep<0xB1>(v);
    v = dpp_addstep<0x1B>(v);
    v = dpp_addstep<0x141>(v);
    v = dpp_addstep<0x140>(v);
    return v;
}

__device__ __forceinline__ unsigned short f2bf(float x) {   // RNE f32->bf16
    unsigned u = __float_as_uint(x);
    return (unsigned short)((u + 0x7FFFu + ((u >> 16) & 1u)) >> 16);
}
__device__ __forceinline__ float bf2f(unsigned short h) {
    return __uint_as_float((unsigned)h << 16);
}

// ---------------- K1: streaming normalize + one-hot MFMA segment-sum ----------------
// R15/R16: 512-thread blocks, CHUNK=32, 33.3KB LDS -> TWO blocks per CU. Same
// 16 waves/CU but two independent barrier domains: when block A's waves sit in
// the chunk barrier, block B's waves issue loads and MFMAs. (R14 proved
// intra-block reordering can't cover the stall.) Wave w owns d-tiles {2w,2w+1}.
#define MPT 512
#define CHUNK 32
#define ROWSTRIDE 260              // u16 units; 520B, qword-stride 65

extern "C" __global__ void __launch_bounds__(MPT)
mfma_main(const float* __restrict__ feats, const int* __restrict__ labels,
          unsigned short* __restrict__ slices, unsigned int* __restrict__ cnts_ws,
          int nrows, int rpb)
{
    __shared__ __align__(16) unsigned short sdat[2][CHUNK * ROWSTRIDE];  // 33.3KB
    __shared__ __align__(8)  unsigned char  slbl[2][CHUNK];
    __shared__ unsigned int scnt[96];

    const int tid  = threadIdx.x;
    const int lane = tid & 63;
    const int w    = tid >> 6;        // wave 0..7
    const int l16  = lane & 15;
    const int g    = lane >> 4;       // lane group 0..3
    const int d0   = w * 32;          // first of two d-tiles
    const int r_loc = tid >> 4;       // row 0..31 this thread stages

    if (tid < 96) scnt[tid] = 0u;

    const int row0 = blockIdx.x * rpb;
    const int nch  = rpb / CHUNK;

    f32x4 accA[6], accB[6];
    #pragma unroll
    for (int ct = 0; ct < 6; ++ct) {
        accA[ct] = (f32x4){0.f, 0.f, 0.f, 0.f};
        accB[ct] = (f32x4){0.f, 0.f, 0.f, 0.f};
    }

    f32x4 pf0, pf1, pf2, pf3;
    int plab;

    auto prefetch = [&](int ch) {
        const int r = row0 + ch * CHUNK + r_loc;
        if (r < nrows) {
            const f32x4* bp = (const f32x4*)(feats + (size_t)r * FDIM + l16 * 16);
            pf0 = __builtin_nontemporal_load(bp);
            pf1 = __builtin_nontemporal_load(bp + 1);
            pf2 = __builtin_nontemporal_load(bp + 2);
            pf3 = __builtin_nontemporal_load(bp + 3);
            plab = labels[r];
        } else {
            pf0 = pf1 = pf2 = pf3 = (f32x4){0.f, 0.f, 0.f, 0.f};
            plab = 255;
        }
    };

    auto stage = [&](int buf) {
        float ss = 0.f;
        #pragma unroll
        for (int k = 0; k < 4; ++k) ss = fmaf(pf0[k], pf0[k], ss);
        #pragma unroll
        for (int k = 0; k < 4; ++k) ss = fmaf(pf1[k], pf1[k], ss);
        #pragma unroll
        for (int k = 0; k < 4; ++k) ss = fmaf(pf2[k], pf2[k], ss);
        #pragma unroll
        for (int k = 0; k < 4; ++k) ss = fmaf(pf3[k], pf3[k], ss);
        ss = group16_sum(ss);        // 16 stagers of a row live in one lane-group
        const float inv = 1.0f / fmaxf(sqrtf(ss), 1e-12f);
        unsigned long long* q =
            (unsigned long long*)&sdat[buf][0] + (size_t)r_loc * 65 + l16 * 4;
        q[0] = (unsigned long long)f2bf(pf0[0] * inv)
             | ((unsigned long long)f2bf(pf0[1] * inv) << 16)
             | ((unsigned long long)f2bf(pf0[2] * inv) << 32)
             | ((unsigned long long)f2bf(pf0[3] * inv) << 48);
        q[1] = (unsigned long long)f2bf(pf1[0] * inv)
             | ((unsigned long long)f2bf(pf1[1] * inv) << 16)
             | ((unsigned long long)f2bf(pf1[2] * inv) << 32)
             | ((unsigned long long)f2bf(pf1[3] * inv) << 48);
        q[2] = (unsigned long long)f2bf(pf2[0] * inv)
             | ((unsigned long long)f2bf(pf2[1] * inv) << 16)
             | ((unsigned long long)f2bf(pf2[2] * inv) << 32)
             | ((unsigned long long)f2bf(pf2[3] * inv) << 48);
        q[3] = (unsigned long long)f2bf(pf3[0] * inv)
             | ((unsigned long long)f2bf(pf3[1] * inv) << 16)
             | ((unsigned long long)f2bf(pf3[2] * inv) << 32)
             | ((unsigned long long)f2bf(pf3[3] * inv) << 48);
        if (l16 == 0) {
            slbl[buf][r_loc] = (unsigned char)plab;
            if (plab < 96) atomicAdd(&scnt[plab], 1u);
        }
    };

    auto mfma_phase = [&](int buf) {
        const int kbase = g * 8;
        const unsigned long long lb =
            *(const unsigned long long*)&slbl[buf][kbase];
        int la[8];
        #pragma unroll
        for (int j = 0; j < 8; ++j) la[j] = (int)((lb >> (8 * j)) & 0xFFu);

        short8 b0, b1;
        #pragma unroll
        for (int j = 0; j < 8; ++j) {
            const unsigned short* rp = &sdat[buf][(size_t)(kbase + j) * ROWSTRIDE];
            b0[j] = (short)rp[d0 + l16];
            b1[j] = (short)rp[d0 + 16 + l16];
        }

        #pragma unroll
        for (int ct = 0; ct < 6; ++ct) {
            const int c = ct * 16 + l16;     // A row m = lane&15
            short8 a;
            #pragma unroll
            for (int j = 0; j < 8; ++j)
                a[j] = (la[j] == c) ? (short)0x3F80 : (short)0;
            accA[ct] = __builtin_amdgcn_mfma_f32_16x16x32_bf16(a, b0, accA[ct], 0, 0, 0);
            accB[ct] = __builtin_amdgcn_mfma_f32_16x16x32_bf16(a, b1, accB[ct], 0, 0, 0);
        }
    };

    // ---- prologue ----
    prefetch(0);
    __syncthreads();                  // scnt init visible before first stage atomic
    stage(0);
    if (nch > 1) prefetch(1);
    __syncthreads();

    // ---- main loop ----
    for (int ch = 0; ch < nch; ++ch) {
        const int cur = ch & 1;
        mfma_phase(cur);
        if (ch + 1 < nch) {
            stage(cur ^ 1);
            if (ch + 2 < nch) prefetch(ch + 2);
        }
        __syncthreads();
    }

    // ---- epilogue: acc -> bf16 via LDS transpose (sdat reused), stream out ----
    unsigned short* es = &sdat[0][0];   // 46.6KB spans both buffers (66.6KB total)
    #pragma unroll
    for (int ct = 0; ct < 6; ++ct) {
        #pragma unroll
        for (int reg = 0; reg < 4; ++reg) {
            const int c = ct * 16 + g * 4 + reg;   // C row = (lane>>4)*4+reg [m89]
            if (c < NCLS) {
                es[c * FDIM + d0 + l16]      = f2bf(accA[ct][reg]);
                es[c * FDIM + d0 + 16 + l16] = f2bf(accB[ct][reg]);
            }
        }
    }
    __syncthreads();
    {
        const unsigned long long* src = (const unsigned long long*)es;
        unsigned long long* dst =
            (unsigned long long*)(slices + (size_t)blockIdx.x * BINSZP);
        for (int i = tid; i < BINSZ / 4; i += MPT) dst[i] = src[i];
    }
    if (tid < 96) cnts_ws[(size_t)blockIdx.x * 96 + tid] = scnt[tid];
}

// ---------------- K2: stage-1 slice reduction (4-class tiles, ulong reads) ----------------
extern "C" __global__ void __launch_bounds__(FDIM)
reduce_k(const unsigned short* __restrict__ slices, float* __restrict__ part2)
{
    const int t4 = blockIdx.x;
    const int h  = blockIdx.y;
    const int t  = threadIdx.x;
    const int off = t4 * 1024 + t * 4;          // u16 offset within a partial
    const int p0 = h * (NB / NRED);

    float s0 = 0.f, s1 = 0.f, s2 = 0.f, s3 = 0.f;
    #pragma unroll 1
    for (int p = 0; p < NB / NRED; p += 4) {
        #pragma unroll
        for (int u = 0; u < 4; ++u) {
            const unsigned long long v = *(const unsigned long long*)
                (slices + (size_t)(p0 + p + u) * BINSZP + off);
            s0 += bf2f((unsigned short)(v));
            s1 += bf2f((unsigned short)(v >> 16));
            s2 += bf2f((unsigned short)(v >> 32));
            s3 += bf2f((unsigned short)(v >> 48));
        }
    }
    float4* dst = (float4*)(part2 + (size_t)h * BINSZP + off);
    *dst = make_float4(s0, s1, s2, s3);
}

// ---------------- bool / scalar dtype detection ----------------
__device__ int detect_bool_enc(const void* p) {
    const unsigned int* u = (const unsigned int*)p;
    bool i32ok = true, f32ok = true;
    for (int i = 0; i < 22; ++i) {
        unsigned int w = u[i];
        if (w > 1u) i32ok = false;
        if (w != 0u && w != 0x3F800000u) f32ok = false;
    }
    return i32ok ? 1 : (f32ok ? 2 : 0);
}
__device__ bool read_bool(const void* p, int enc, int i) {
    if (enc == 1) return ((const unsigned int*)p)[i] != 0u;
    if (enc == 2) return ((const float*)p)[i] != 0.0f;
    return ((const unsigned char*)p)[i] != 0;
}
__device__ int read_step(const void* p) {
    unsigned int w = ((const unsigned int*)p)[0];
    int iv = (int)w;
    if (iv >= 0 && iv < 16777216) return iv;
    return (int)__uint_as_float(w);
}

// ---------------- K3: final per-class math ----------------
extern "C" __global__ void __launch_bounds__(FDIM)
final_k(const float* __restrict__ part2, const unsigned int* __restrict__ cnts_ws,
        const float* __restrict__ protos, const void* __restrict__ p_init,
        const float* __restrict__ p_var, const float* __restrict__ shadow,
        const void* __restrict__ s_init, const int* __restrict__ p_count,
        const void* __restrict__ p_step, float* __restrict__ out)
{
    const int c = blockIdx.x;
    const int d = threadIdx.x;

    __shared__ int enc_pi, enc_si;
    __shared__ float red[FDIM / 64];
    __shared__ int credi[FDIM / 64];
    __shared__ float s_upd;
    __shared__ unsigned int s_cnt;
    if (d == 0) { enc_pi = detect_bool_enc(p_init); enc_si = detect_bool_enc(s_init); }

    int cpart = 0;
    for (int p = d; p < NB; p += FDIM)
        cpart += (int)cnts_ws[(size_t)p * 96 + c];
    int cw = wave_sum64_i(cpart);
    if ((d & 63) == 0) credi[d >> 6] = cw;
    __syncthreads();
    if (d == 0) s_cnt = (unsigned int)(credi[0] + credi[1] + credi[2] + credi[3]);

    const int slot = c * FDIM + d;
    float sum = 0.f;
    #pragma unroll
    for (int h = 0; h < NRED; ++h) sum += part2[(size_t)h * BINSZP + slot];
    __syncthreads();

    const unsigned int cnt = s_cnt;
    const bool present = cnt > 0u;
    const float cls = sum / fmaxf((float)cnt, 1.0f);
    const float oldp = protos[c * FDIM + d];

    const float diff = cls - oldp;
    float ds = wave_sum64(diff * diff);
    if ((d & 63) == 0) red[d >> 6] = ds;
    __syncthreads();
    if (d == 0) s_upd = sqrtf(red[0] + red[1] + red[2] + red[3] + 1e-24f);
    __syncthreads();
    const float upd_mag = s_upd;

    const bool  init  = read_bool(p_init, enc_pi, c);
    const bool  sinit = read_bool(s_init, enc_si, c);
    const float var   = p_var[c];
    const int   step  = read_step(p_step);

    const float progress = fminf(1.0f, (float)step * (1.0f / 2000.0f));
    const float mom = init ? (0.99f + 0.009f * expf(-var) * progress) : 0.99f;

    const float ema   = mom * oldp + (1.0f - mom) * cls;
    const float newp  = present ? (init ? ema : cls) : oldp;

    const float sh     = shadow[c * FDIM + d];
    const float sh_ema = 0.9999f * sh + 0.0001f * newp;
    const float newsh  = present ? (sinit ? sh_ema : newp) : sh;

    const int O1 = NCLS * FDIM;
    const int O2 = O1 + NCLS;
    const int O3 = O2 + NCLS * FDIM;
    const int O4 = O3 + NCLS;
    const int O5 = O4 + NCLS;

    out[c * FDIM + d]       = newp;
    out[O2 + c * FDIM + d]  = newsh;
    if (d == 0) {
        const float newvar = (present && init) ? (0.99f * var + 0.01f * upd_mag) : var;
        out[O1 + c] = newvar;
        out[O3 + c] = (init || present)  ? 1.0f : 0.0f;
        out[O4 + c] = (sinit || present) ? 1.0f : 0.0f;
        out[O5 + c] = (float)(p_count[c] + (present ? 1 : 0));
    }
}

extern "C" void kernel_launch(void* const* d_in, const int* in_sizes, int n_in,
                              void* d_out, int out_size, void* d_ws, size_t ws_size,
                              hipStream_t stream) {
    const float* feats  = (const float*)d_in[0];
    const int*   labels = (const int*)d_in[1];
    const float* protos = (const float*)d_in[2];
    const void*  p_init = d_in[3];
    const float* p_var  = (const float*)d_in[4];
    const float* shadow = (const float*)d_in[5];
    const void*  s_init = d_in[6];
    const int*   p_cnt  = (const int*)d_in[7];
    const void*  p_step = d_in[8];
    const int nrows = in_sizes[1];

    int rpb = (nrows + NB - 1) / NB;
    rpb = ((rpb + CHUNK - 1) / CHUNK) * CHUNK;

    unsigned short* slices  = (unsigned short*)d_ws;                 // [NB][BINSZP] bf16
    unsigned int*   cnts_ws = (unsigned int*)((char*)d_ws + (size_t)BINSZP * NB * 2);
    float*          part2   = (float*)((char*)d_ws + (size_t)BINSZP * NB * 2
                                       + (size_t)NB * 96 * 4);       // [NRED][BINSZP]

    mfma_main<<<NB, MPT, 0, stream>>>(feats, labels, slices, cnts_ws, nrows, rpb);
    reduce_k<<<dim3(23, NRED), FDIM, 0, stream>>>(slices, part2);
    final_k<<<NCLS, FDIM, 0, stream>>>(part2, cnts_ws, protos, p_init, p_var,
                                       shadow, s_init, p_cnt, p_step, (float*)d_out);
}

// Round 18
// 48.499 us; speedup vs baseline: 1.3163x; 1.3163x over previous
//
#include <hip/hip_runtime.h>
#include <math.h>

#define NCLS 91
#define FDIM 256
#define NB   256                   // mainpass blocks (= partials), 1 per CU
#define BINSZ (NCLS * FDIM)        // 23296
#define NRED 8                     // stage-1 reduction: 8 groups of 32

typedef float f32x4 __attribute__((ext_vector_type(4)));
typedef short short8 __attribute__((ext_vector_type(8)));

__device__ __forceinline__ float wave_sum64(float ss) {
    #pragma unroll
    for (int m = 1; m < 64; m <<= 1) ss += __shfl_xor(ss, m, 64);
    return ss;
}
__device__ __forceinline__ int wave_sum64_i(int v) {
    #pragma unroll
    for (int m = 1; m < 64; m <<= 1) v += __shfl_xor(v, m, 64);
    return v;
}

// pure-DPP 16-lane butterfly (VALU only) — verified R9
template <int CTRL>
__device__ __forceinline__ float dpp_addstep(float v) {
    return v + __int_as_float(__builtin_amdgcn_mov_dpp(
        __float_as_int(v), CTRL, 0xf, 0xf, true));
}
__device__ __forceinline__ float group16_sum(float v) {
    v = dpp_addstep<0xB1>(v);
    v = dpp_addstep<0x1B>(v);
    v = dpp_addstep<0x141>(v);
    v = dpp_addstep<0x140>(v);
    return v;
}

__device__ __forceinline__ unsigned short f2bf(float x) {   // RNE f32->bf16
    unsigned u = __float_as_uint(x);
    return (unsigned short)((u + 0x7FFFu + ((u >> 16) & 1u)) >> 16);
}
__device__ __forceinline__ float bf2f(unsigned short h) {
    return __uint_as_float((unsigned)h << 16);
}

// ---------------- K1: streaming normalize + one-hot MFMA segment-sum ----------------
// Best-known config (R13, 48.66us): S[c,d] = sum_k onehot[c,k]*fnorm[k,d] via
// mfma_f32_16x16x32_bf16 — per-class accumulation in AGPRs, zero per-row
// atomics (R0/R1/R2/R9 wall: LDS f32 atomics serialize per-lane ~3.2cy/lane),
// zero gather (R3-R8 wall: sorted-gather latency-bound ~80us even L3-warm).
// R14 (load reorder) neutral; R15/R16 (2 blocks/CU) regressed — reverted.
#define MPT 1024
#define CHUNK 64
#define ROWSTRIDE 260              // u16 units; 520B, qword-stride 65

extern "C" __global__ void __launch_bounds__(MPT)
mfma_main(const float* __restrict__ feats, const int* __restrict__ labels,
          unsigned short* __restrict__ slices, unsigned int* __restrict__ cnts_ws,
          int nrows, int rpb)
{
    __shared__ __align__(16) unsigned short sdat[2][CHUNK * ROWSTRIDE];  // 66.6KB
    __shared__ __align__(8)  unsigned char  slbl[2][CHUNK];
    __shared__ unsigned int scnt[96];

    const int tid  = threadIdx.x;
    const int lane = tid & 63;
    const int w    = tid >> 6;        // wave 0..15 -> d-tile
    const int l16  = lane & 15;
    const int g    = lane >> 4;       // lane group 0..3
    const int d0   = w * 16;
    const int r_loc = w * 4 + g;      // the row this lane stages

    if (tid < 96) scnt[tid] = 0u;

    const int row0 = blockIdx.x * rpb;
    const int nch  = rpb / CHUNK;

    f32x4 acc[6];
    #pragma unroll
    for (int ct = 0; ct < 6; ++ct) acc[ct] = (f32x4){0.f, 0.f, 0.f, 0.f};

    float4 pf0, pf1, pf2, pf3;
    int plab;

    {   // load chunk 0
        const int r = row0 + r_loc;
        if (r < nrows) {
            const float4* bp = (const float4*)(feats + (size_t)r * FDIM + l16 * 16);
            pf0 = bp[0]; pf1 = bp[1]; pf2 = bp[2]; pf3 = bp[3];
            plab = labels[r];
        } else {
            pf0 = pf1 = pf2 = pf3 = make_float4(0.f, 0.f, 0.f, 0.f);
            plab = 255;
        }
    }

    auto stage = [&](int buf) {
        float ss = 0.f;
        ss = fmaf(pf0.x, pf0.x, ss); ss = fmaf(pf0.y, pf0.y, ss);
        ss = fmaf(pf0.z, pf0.z, ss); ss = fmaf(pf0.w, pf0.w, ss);
        ss = fmaf(pf1.x, pf1.x, ss); ss = fmaf(pf1.y, pf1.y, ss);
        ss = fmaf(pf1.z, pf1.z, ss); ss = fmaf(pf1.w, pf1.w, ss);
        ss = fmaf(pf2.x, pf2.x, ss); ss = fmaf(pf2.y, pf2.y, ss);
        ss = fmaf(pf2.z, pf2.z, ss); ss = fmaf(pf2.w, pf2.w, ss);
        ss = fmaf(pf3.x, pf3.x, ss); ss = fmaf(pf3.y, pf3.y, ss);
        ss = fmaf(pf3.z, pf3.z, ss); ss = fmaf(pf3.w, pf3.w, ss);
        ss = group16_sum(ss);
        const float inv = 1.0f / fmaxf(sqrtf(ss), 1e-12f);
        unsigned long long* q =
            (unsigned long long*)&sdat[buf][0] + (size_t)r_loc * 65 + l16 * 4;
        const float e[16] = {pf0.x, pf0.y, pf0.z, pf0.w, pf1.x, pf1.y, pf1.z, pf1.w,
                             pf2.x, pf2.y, pf2.z, pf2.w, pf3.x, pf3.y, pf3.z, pf3.w};
        #pragma unroll
        for (int t = 0; t < 4; ++t) {
            unsigned long long v =
                (unsigned long long)f2bf(e[4 * t + 0] * inv)
              | ((unsigned long long)f2bf(e[4 * t + 1] * inv) << 16)
              | ((unsigned long long)f2bf(e[4 * t + 2] * inv) << 32)
              | ((unsigned long long)f2bf(e[4 * t + 3] * inv) << 48);
            q[t] = v;
        }
        if (l16 == 0) {
            slbl[buf][r_loc] = (unsigned char)plab;
            if (plab < 96) atomicAdd(&scnt[plab], 1u);
        }
    };
    auto prefetch = [&](int ch_next) {
        const int r = row0 + ch_next * CHUNK + r_loc;
        if (r < nrows) {
            const float4* bp = (const float4*)(feats + (size_t)r * FDIM + l16 * 16);
            pf0 = bp[0]; pf1 = bp[1]; pf2 = bp[2]; pf3 = bp[3];
            plab = labels[r];
        } else {
            pf0 = pf1 = pf2 = pf3 = make_float4(0.f, 0.f, 0.f, 0.f);
            plab = 255;
        }
    };

    __syncthreads();                  // scnt init visible before first stage atomic
    stage(0);
    if (nch > 1) prefetch(1);
    __syncthreads();

    for (int ch = 0; ch < nch; ++ch) {
        const int cur = ch & 1;
        #pragma unroll
        for (int s = 0; s < 2; ++s) {
            const int kbase = s * 32 + g * 8;
            const unsigned long long lb =
                *(const unsigned long long*)&slbl[cur][kbase];
            int la[8];
            #pragma unroll
            for (int j = 0; j < 8; ++j) la[j] = (int)((lb >> (8 * j)) & 0xFFu);

            short8 b;
            #pragma unroll
            for (int j = 0; j < 8; ++j)
                b[j] = (short)sdat[cur][(size_t)(kbase + j) * ROWSTRIDE + d0 + l16];

            #pragma unroll
            for (int ct = 0; ct < 6; ++ct) {
                const int c = ct * 16 + l16;     // A row m = lane&15
                short8 a;
                #pragma unroll
                for (int j = 0; j < 8; ++j)
                    a[j] = (la[j] == c) ? (short)0x3F80 : (short)0;
                acc[ct] = __builtin_amdgcn_mfma_f32_16x16x32_bf16(a, b, acc[ct], 0, 0, 0);
            }
        }
        if (ch + 1 < nch) {
            stage(cur ^ 1);
            if (ch + 2 < nch) prefetch(ch + 2);
        }
        __syncthreads();
    }

    // ---- epilogue: acc -> bf16 via LDS transpose (sdat[0] = 33.3KB >= 46.6KB/2?
    // es spans both buffers: 2*CHUNK*ROWSTRIDE*2B = 66.6KB >= 46.6KB needed) ----
    unsigned short* es = &sdat[0][0];
    #pragma unroll
    for (int ct = 0; ct < 6; ++ct) {
        #pragma unroll
        for (int reg = 0; reg < 4; ++reg) {
            const int c = ct * 16 + g * 4 + reg;   // C row = (lane>>4)*4+reg [m89]
            if (c < NCLS)
                es[c * FDIM + d0 + l16] = f2bf(acc[ct][reg]);
        }
    }
    __syncthreads();
    {   // coalesced stream-out: 23296 u16 = 2912 ulong (8B each)
        const unsigned long long* src = (const unsigned long long*)es;
        unsigned long long* dst =
            (unsigned long long*)(slices + (size_t)blockIdx.x * BINSZ);
        for (int i = tid; i < BINSZ / 4; i += MPT) dst[i] = src[i];
    }
    if (tid < 96) cnts_ws[(size_t)blockIdx.x * 96 + tid] = scnt[tid];
}

// ---------------- K2: stage-1 slice reduction ----------------
// grid (NCLS, NRED): block (c,h) reduces partials [h*32, h*32+32) for class c.
extern "C" __global__ void __launch_bounds__(FDIM)
reduce_k(const unsigned short* __restrict__ slices, float* __restrict__ part2)
{
    const int c = blockIdx.x;
    const int h = blockIdx.y;
    const int d = threadIdx.x;
    const int slot = c * FDIM + d;
    const int p0 = h * (NB / NRED);

    float a0 = 0.f, a1 = 0.f, a2 = 0.f, a3 = 0.f;
    #pragma unroll 1
    for (int p = 0; p < NB / NRED; p += 4) {
        a0 += bf2f(slices[(size_t)(p0 + p + 0) * BINSZ + slot]);
        a1 += bf2f(slices[(size_t)(p0 + p + 1) * BINSZ + slot]);
        a2 += bf2f(slices[(size_t)(p0 + p + 2) * BINSZ + slot]);
        a3 += bf2f(slices[(size_t)(p0 + p + 3) * BINSZ + slot]);
    }
    part2[(size_t)h * BINSZ + slot] = (a0 + a1) + (a2 + a3);
}

// ---------------- bool / scalar dtype detection ----------------
__device__ int detect_bool_enc(const void* p) {
    const unsigned int* u = (const unsigned int*)p;
    bool i32ok = true, f32ok = true;
    for (int i = 0; i < 22; ++i) {
        unsigned int w = u[i];
        if (w > 1u) i32ok = false;
        if (w != 0u && w != 0x3F800000u) f32ok = false;
    }
    return i32ok ? 1 : (f32ok ? 2 : 0);
}
__device__ bool read_bool(const void* p, int enc, int i) {
    if (enc == 1) return ((const unsigned int*)p)[i] != 0u;
    if (enc == 2) return ((const float*)p)[i] != 0.0f;
    return ((const unsigned char*)p)[i] != 0;
}
__device__ int read_step(const void* p) {
    unsigned int w = ((const unsigned int*)p)[0];
    int iv = (int)w;
    if (iv >= 0 && iv < 16777216) return iv;
    return (int)__uint_as_float(w);
}

// ---------------- K3: final per-class math ----------------
extern "C" __global__ void __launch_bounds__(FDIM)
final_k(const float* __restrict__ part2, const unsigned int* __restrict__ cnts_ws,
        const float* __restrict__ protos, const void* __restrict__ p_init,
        const float* __restrict__ p_var, const float* __restrict__ shadow,
        const void* __restrict__ s_init, const int* __restrict__ p_count,
        const void* __restrict__ p_step, float* __restrict__ out)
{
    const int c = blockIdx.x;
    const int d = threadIdx.x;

    __shared__ int enc_pi, enc_si;
    __shared__ float red[FDIM / 64];
    __shared__ int credi[FDIM / 64];
    __shared__ float s_upd;
    __shared__ unsigned int s_cnt;
    if (d == 0) { enc_pi = detect_bool_enc(p_init); enc_si = detect_bool_enc(s_init); }

    int cpart = 0;
    for (int p = d; p < NB; p += FDIM)
        cpart += (int)cnts_ws[(size_t)p * 96 + c];
    int cw = wave_sum64_i(cpart);
    if ((d & 63) == 0) credi[d >> 6] = cw;
    __syncthreads();
    if (d == 0) s_cnt = (unsigned int)(credi[0] + credi[1] + credi[2] + credi[3]);

    const int slot = c * FDIM + d;
    float sum = 0.f;
    #pragma unroll
    for (int h = 0; h < NRED; ++h) sum += part2[(size_t)h * BINSZ + slot];
    __syncthreads();

    const unsigned int cnt = s_cnt;
    const bool present = cnt > 0u;
    const float cls = sum / fmaxf((float)cnt, 1.0f);
    const float oldp = protos[c * FDIM + d];

    const float diff = cls - oldp;
    float ds = wave_sum64(diff * diff);
    if ((d & 63) == 0) red[d >> 6] = ds;
    __syncthreads();
    if (d == 0) s_upd = sqrtf(red[0] + red[1] + red[2] + red[3] + 1e-24f);
    __syncthreads();
    const float upd_mag = s_upd;

    const bool  init  = read_bool(p_init, enc_pi, c);
    const bool  sinit = read_bool(s_init, enc_si, c);
    const float var   = p_var[c];
    const int   step  = read_step(p_step);

    const float progress = fminf(1.0f, (float)step * (1.0f / 2000.0f));
    const float mom = init ? (0.99f + 0.009f * expf(-var) * progress) : 0.99f;

    const float ema   = mom * oldp + (1.0f - mom) * cls;
    const float newp  = present ? (init ? ema : cls) : oldp;

    const float sh     = shadow[c * FDIM + d];
    const float sh_ema = 0.9999f * sh + 0.0001f * newp;
    const float newsh  = present ? (sinit ? sh_ema : newp) : sh;

    const int O1 = NCLS * FDIM;
    const int O2 = O1 + NCLS;
    const int O3 = O2 + NCLS * FDIM;
    const int O4 = O3 + NCLS;
    const int O5 = O4 + NCLS;

    out[c * FDIM + d]       = newp;
    out[O2 + c * FDIM + d]  = newsh;
    if (d == 0) {
        const float newvar = (present && init) ? (0.99f * var + 0.01f * upd_mag) : var;
        out[O1 + c] = newvar;
        out[O3 + c] = (init || present)  ? 1.0f : 0.0f;
        out[O4 + c] = (sinit || present) ? 1.0f : 0.0f;
        out[O5 + c] = (float)(p_count[c] + (present ? 1 : 0));
    }
}

extern "C" void kernel_launch(void* const* d_in, const int* in_sizes, int n_in,
                              void* d_out, int out_size, void* d_ws, size_t ws_size,
                              hipStream_t stream) {
    const float* feats  = (const float*)d_in[0];
    const int*   labels = (const int*)d_in[1];
    const float* protos = (const float*)d_in[2];
    const void*  p_init = d_in[3];
    const float* p_var  = (const float*)d_in[4];
    const float* shadow = (const float*)d_in[5];
    const void*  s_init = d_in[6];
    const int*   p_cnt  = (const int*)d_in[7];
    const void*  p_step = d_in[8];
    const int nrows = in_sizes[1];

    int rpb = (nrows + NB - 1) / NB;
    rpb = ((rpb + CHUNK - 1) / CHUNK) * CHUNK;

    unsigned short* slices  = (unsigned short*)d_ws;                 // [NB][BINSZ] bf16
    unsigned int*   cnts_ws = (unsigned int*)((char*)d_ws + (size_t)BINSZ * NB * 2);
    float*          part2   = (float*)((char*)d_ws + (size_t)BINSZ * NB * 2
                                       + (size_t)NB * 96 * 4);       // [NRED][BINSZ]

    mfma_main<<<NB, MPT, 0, stream>>>(feats, labels, slices, cnts_ws, nrows, rpb);
    reduce_k<<<dim3(NCLS, NRED), FDIM, 0, stream>>>(slices, part2);
    final_k<<<NCLS, FDIM, 0, stream>>>(part2, cnts_ws, protos, p_init, p_var,
                                       shadow, s_init, p_cnt, p_step, (float*)d_out);
}